// Round 11
// baseline (50.344 us; speedup 1.0000x reference)
//
#include <hip/hip_runtime.h>

// B=8, C=512, T=8192, RATIO=2, K=12
#define T_LEN 8192
#define C_N   512
#define BLOCK 256
#define OPT   8                       // outputs per thread per chunk
#define TCHUNK (BLOCK * OPT)          // 2048
#define NCHUNK 4
#define NVIRT  (2 * NCHUNK)           // 2 rows x 4 chunks per block
#define INV_2PI 0.15915494309189535f

typedef float f32x2 __attribute__((ext_vector_type(2)));

// Verified formulas (ground truth = rounds 0-9, all passing):
//   y[2i]   = 2 * sum_t wup[2t+1] * xc[i+2-t]   (t=0..5, xc = edge-clamped x)
//   y[2i+1] = 2 * sum_t wup[2t]   * xc[i+3-t]
//   snake:   y += sin(a*y)^2 / (a+1e-9)
//   out[n]  = sum_k wdn[k] * ypad[2n-5+k]       (ypad = edge-clamped y)
//
// Packed-f32 formulation (v_pk_fma_f32), R6 winner:
//   A_p := (yv[2p], yv[2p-1]), p=1..8, yv[u] = y[2N-6+u]
//   A_p = sum_t cpair[t] * splat(xr[7+p-t]),  cpair[t]=(u2[2t+1], u2[2t])
//   out[N+r] = sum_j dpair[j] (.) A_{r+j+1},  dpair[j]=(wdn[2j+1], wdn[2j])
//   A_{8+p} = shfl_down(A_p); lane 63 gathers lane-parallel halo yh
//     (lane v=2s+par: yh = y[2(N63+5+s)+par], taps xt[j]=xc[N63+2+s+par+j])
//
// R10: machine-exactly-filling persistent grid. 2048 blocks = 8 blocks/CU =
// 32 waves/CU resident at VGPR<=64 -> single dispatch round, no churn.
// Each block: rows bc and bc+2048 (same channel -> shared alpha/coeffs),
// 8 virtual chunks, R9 forced prefetch carried across the row boundary.

__global__ __launch_bounds__(BLOCK, 4) void act1d_fused(
    const float* __restrict__ x,
    const float* __restrict__ alpha,
    const float* __restrict__ wup_g,
    const float* __restrict__ wdn_g,
    float* __restrict__ out)
{
    const int bc0  = blockIdx.x;            // first row; second is bc0+2048
    const int c    = bc0 & (C_N - 1);       // same for both rows
    const int tid  = threadIdx.x;
    const int lane = tid & 63;
    const int s_   = lane >> 1;
    const int par  = lane & 1;
    const int b63  = OPT * (tid - lane + 63);   // lane-63 N offset (wave-uniform)

    const float* __restrict__ xrow0 = x   + (size_t)bc0 * T_LEN;
    float*       __restrict__ orow0 = out + (size_t)bc0 * T_LEN;
    const float* __restrict__ xrow1 = xrow0 + (size_t)2048 * T_LEN;
    float*       __restrict__ orow1 = orow0 + (size_t)2048 * T_LEN;

    // ---- prologue: virtual chunk 0 (row 0, chunk 0) memory ----
    float xr[16], xt[6];
    {
        const int N = OPT * tid;
        if (N >= 8) {
#pragma unroll
            for (int w = 0; w < 4; ++w) {
                const float4 t4 = *reinterpret_cast<const float4*>(xrow0 + N - 8 + 4 * w);
                xr[4 * w + 0] = t4.x;
                xr[4 * w + 1] = t4.y;
                xr[4 * w + 2] = t4.z;
                xr[4 * w + 3] = t4.w;
            }
        } else {   // tid==0 only: left edge clamp
#pragma unroll
            for (int u = 0; u < 16; ++u)
                xr[u] = xrow0[max(N - 8 + u, 0)];
        }
        const int hb = b63 + 2 + s_ + par;      // chunk 0: always in range
#pragma unroll
        for (int j = 0; j < 6; ++j)
            xt[j] = xrow0[hb + j];
    }

    // ---- uniform constants (wave-uniform -> SGPRs; shared by both rows) ----
    f32x2 cpair[6], dpair[6];
#pragma unroll
    for (int t = 0; t < 6; ++t) {
        cpair[t] = (f32x2){ wup_g[2 * t + 1] + wup_g[2 * t + 1],
                            wup_g[2 * t]     + wup_g[2 * t] };
        dpair[t] = (f32x2){ wdn_g[2 * t + 1], wdn_g[2 * t] };
    }
    const float a     = __expf(alpha[c]);
    const float inv_a = 1.0f / (a + 1e-9f);
    const float ka    = a * INV_2PI;    // v_sin_f32 takes revolutions
    const f32x2 ka2   = (f32x2){ ka, ka };
    const f32x2 inva2 = (f32x2){ inv_a, inv_a };

#pragma unroll
    for (int v = 0; v < NVIRT; ++v) {
        const int row = v >> 2;                 // compile-time after unroll
        const int ch  = v & 3;
        const float* __restrict__ xrow = row ? xrow1 : xrow0;
        float*       __restrict__ orow = row ? orow1 : orow0;
        const int N   = ch * TCHUNK + OPT * tid;
        const int N63 = ch * TCHUNK + b63;

        // ---- prefetch virtual chunk v+1's ENTIRE memory (issue-early) ----
        float xrN[16], xtN[6];
        if (v < NVIRT - 1) {
            const int rn = (v + 1) >> 2;
            const int cn = (v + 1) & 3;
            const float* __restrict__ xrn = rn ? xrow1 : xrow0;
            const int Nn = cn * TCHUNK + OPT * tid;
            if (Nn >= 8) {                     // false only: cn==0 && tid==0
#pragma unroll
                for (int w = 0; w < 4; ++w) {
                    const float4 t4 = *reinterpret_cast<const float4*>(xrn + Nn - 8 + 4 * w);
                    xrN[4 * w + 0] = t4.x;
                    xrN[4 * w + 1] = t4.y;
                    xrN[4 * w + 2] = t4.z;
                    xrN[4 * w + 3] = t4.w;
                }
            } else {
#pragma unroll
                for (int u = 0; u < 16; ++u)
                    xrN[u] = xrn[max(Nn - 8 + u, 0)];
            }
            const int N63n = cn * TCHUNK + b63;
            const int hbn  = N63n + 2 + s_ + par;
            if (N63n + 12 < T_LEN) {           // wave-uniform fast path
#pragma unroll
                for (int j = 0; j < 6; ++j)
                    xtN[j] = xrn[hbn + j];
            } else {                            // last wave of chunk 3 only
#pragma unroll
                for (int j = 0; j < 6; ++j)
                    xtN[j] = xrn[min(hbn + j, T_LEN - 1)];
            }
        }

        // ---- pin: loads stay above, compute below (wait lands at use) ----
        asm volatile("" ::: "memory");
        __builtin_amdgcn_sched_barrier(0);

        // ---- upsample, packed: A[p] = (yv[2p], yv[2p-1]), p=1..8 ----
        f32x2 A[14];
#pragma unroll
        for (int p = 1; p <= 8; ++p)
            A[p] = (f32x2){ 0.0f, 0.0f };
#pragma unroll
        for (int u = 3; u <= 15; ++u) {
            const f32x2 su = (f32x2){ xr[u], xr[u] };
#pragma unroll
            for (int t = 0; t < 6; ++t) {
                const int p = u - 7 + t;
                if (p >= 1 && p <= 8)
                    A[p] = __builtin_elementwise_fma(cpair[t], su, A[p]);
            }
        }

        // ---- lane-parallel halo y (lane w<11 real, others harmless) ----
        float yh = 0.0f;
#pragma unroll
        for (int j = 0; j < 6; ++j) {
            const float cj = par ? cpair[5 - j].y : cpair[5 - j].x;
            yh = fmaf(cj, xt[j], yh);
        }
        {
            const float s = __builtin_amdgcn_sinf(ka * yh);
            yh = fmaf(s * s, inv_a, yh);
        }

        // ---- snake, packed (scalar v_sin per half) ----
#pragma unroll
        for (int p = 1; p <= 8; ++p) {
            const f32x2 arg = A[p] * ka2;
            const f32x2 s   = (f32x2){ __builtin_amdgcn_sinf(arg.x),
                                       __builtin_amdgcn_sinf(arg.y) };
            A[p] = __builtin_elementwise_fma(s * s, inva2, A[p]);
        }

        // ---- left edge: ypad[m<0] = y[0]  (yv[1..5]=yv[6], only N==0) ----
        if (N == 0) {
            const float vv = A[3].x;      // snaked yv[6]
            A[1] = (f32x2){ vv, vv };
            A[2] = (f32x2){ vv, vv };
            A[3].y = vv;
        }

        // ---- halo pairs A[9..13]: shfl_down(A[1..5]); lane63 readlane ----
        const bool is63 = (lane == 63);
#pragma unroll
        for (int p = 1; p <= 5; ++p) {
            const float dx = __shfl_down(A[p].x, 1, 64);
            const float dy = __shfl_down(A[p].y, 1, 64);
            const float gx = __int_as_float(
                __builtin_amdgcn_readlane(__float_as_int(yh), 2 * p));
            const float gy = __int_as_float(
                __builtin_amdgcn_readlane(__float_as_int(yh), 2 * p - 1));
            A[8 + p] = (f32x2){ is63 ? gx : dx, is63 ? gy : dy };
        }

        // ---- right edge: ypad[m>16383] = y[16383]  (h[6..10]=h[5]) ----
        if (N == T_LEN - OPT) {
            const float h5 = A[11].y;
            A[11] = (f32x2){ h5, h5 };
            A[12] = (f32x2){ h5, h5 };
            A[13] = (f32x2){ h5, h5 };
        }

        // ---- downsample, packed: o_r = sum_j dpair[j] (.) A[r+j+1] ----
        float o[OPT];
#pragma unroll
        for (int r = 0; r < OPT; ++r) {
            f32x2 P = dpair[0] * A[r + 1];
#pragma unroll
            for (int j = 1; j < 6; ++j)
                P = __builtin_elementwise_fma(dpair[j], A[r + j + 1], P);
            o[r] = P.x + P.y;
        }

        *reinterpret_cast<float4*>(orow + N)     = make_float4(o[0], o[1], o[2], o[3]);
        *reinterpret_cast<float4*>(orow + N + 4) = make_float4(o[4], o[5], o[6], o[7]);

        // ---- rotate prefetch buffers (renamed away by full unroll) ----
        if (v < NVIRT - 1) {
#pragma unroll
            for (int u = 0; u < 16; ++u)
                xr[u] = xrN[u];
#pragma unroll
            for (int j = 0; j < 6; ++j)
                xt[j] = xtN[j];
        }
    }
}

extern "C" void kernel_launch(void* const* d_in, const int* in_sizes, int n_in,
                              void* d_out, int out_size, void* d_ws, size_t ws_size,
                              hipStream_t stream)
{
    const float* x     = (const float*)d_in[0];
    const float* alpha = (const float*)d_in[1];
    const float* wup   = (const float*)d_in[2];
    const float* wdn   = (const float*)d_in[3];
    float*       out   = (float*)d_out;

    const int total_rows = out_size / T_LEN;     // 4096
    const int grid       = total_rows / 2;       // 2048: rows bc and bc+2048

    act1d_fused<<<grid, BLOCK, 0, stream>>>(x, alpha, wup, wdn, out);
}

// Round 12
// 47.583 us; speedup vs baseline: 1.0580x; 1.0580x over previous
//
#include <hip/hip_runtime.h>

// B=8, C=512, T=8192, RATIO=2, K=12
#define T_LEN 8192
#define C_N   512
#define BLOCK 256
#define OPT   8                       // outputs per thread per segment
#define TCHUNK (BLOCK * OPT)          // 2048
#define INV_2PI 0.15915494309189535f

typedef float f32x2 __attribute__((ext_vector_type(2)));

// Verified formulas (ground truth = rounds 0-10, all passing):
//   y[2i]   = 2 * sum_t wup[2t+1] * xc[i+2-t]   (t=0..5, xc = edge-clamped x)
//   y[2i+1] = 2 * sum_t wup[2t]   * xc[i+3-t]
//   snake:   y += sin(a*y)^2 / (a+1e-9)
//   out[n]  = sum_k wdn[k] * ypad[2n-5+k]       (ypad = edge-clamped y)
//
// Packed-f32 formulation (v_pk_fma_f32), R6 winner:
//   A_p := (yv[2p], yv[2p-1]), p=1..8, yv[u] = y[2N-6+u]
//   A_p = sum_t cpair[t] * splat(xr[7+p-t]),  cpair[t]=(u2[2t+1], u2[2t])
//   out[N+r] = sum_j dpair[j] (.) A_{r+j+1},  dpair[j]=(wdn[2j+1], wdn[2j])
//   A_{8+p} = shfl_down(A_p); lane 63 gathers lane-parallel halo yh
//     (lane v=2s+par: yh = y[2(N63+5+s)+par], taps xt[j]=xc[N63+2+s+par+j])
//
// R11: clean test of the latency-hiding hypothesis. Straight-line 2-segment
// pipeline (R3's structure, which held at VGPR=64) + packed compute (R6).
// ALL 20 VMEM ops (xrA 4x dwordx4, xtA 6, xrB 4x dwordx4, xtB 6) issue before
// any compute; pinned by asm memory clobber + sched_barrier(0). Segment B's
// HBM latency hides under segment A's ~400-cycle compute. Edge handling is
// template-pruned: A can only hit the left edge, B only the right.
// Verification handle: VGPR_Count must be ~85-110 (both windows live).

template<bool LEFT, bool RIGHT>
__device__ __forceinline__ void compute_store(
    const float* __restrict__ xr, const float* __restrict__ xt,
    int N, int lane, int par,
    float* __restrict__ orow,
    const f32x2* __restrict__ cpair, const f32x2* __restrict__ dpair,
    float inv_a, float ka, f32x2 ka2, f32x2 inva2)
{
    // ---- upsample, packed: A[p] = (yv[2p], yv[2p-1]), p=1..8 ----
    f32x2 A[14];
#pragma unroll
    for (int p = 1; p <= 8; ++p)
        A[p] = (f32x2){ 0.0f, 0.0f };
#pragma unroll
    for (int u = 3; u <= 15; ++u) {
        const f32x2 su = (f32x2){ xr[u], xr[u] };
#pragma unroll
        for (int t = 0; t < 6; ++t) {
            const int p = u - 7 + t;
            if (p >= 1 && p <= 8)
                A[p] = __builtin_elementwise_fma(cpair[t], su, A[p]);
        }
    }

    // ---- lane-parallel halo y (lane v<11 real, others harmless) ----
    float yh = 0.0f;
#pragma unroll
    for (int j = 0; j < 6; ++j) {
        const float cj = par ? cpair[5 - j].y : cpair[5 - j].x;
        yh = fmaf(cj, xt[j], yh);
    }
    {
        const float s = __builtin_amdgcn_sinf(ka * yh);
        yh = fmaf(s * s, inv_a, yh);
    }

    // ---- snake, packed (scalar v_sin per half) ----
#pragma unroll
    for (int p = 1; p <= 8; ++p) {
        const f32x2 arg = A[p] * ka2;
        const f32x2 s   = (f32x2){ __builtin_amdgcn_sinf(arg.x),
                                   __builtin_amdgcn_sinf(arg.y) };
        A[p] = __builtin_elementwise_fma(s * s, inva2, A[p]);
    }

    // ---- left edge: ypad[m<0] = y[0]  (yv[1..5]=yv[6], only N==0) ----
    if (LEFT) {
        if (N == 0) {
            const float v = A[3].x;       // snaked yv[6]
            A[1] = (f32x2){ v, v };
            A[2] = (f32x2){ v, v };
            A[3].y = v;
        }
    }

    // ---- halo pairs A[9..13]: shfl_down(A[1..5]); lane63 readlane ----
    const bool is63 = (lane == 63);
#pragma unroll
    for (int p = 1; p <= 5; ++p) {
        const float dx = __shfl_down(A[p].x, 1, 64);
        const float dy = __shfl_down(A[p].y, 1, 64);
        const float gx = __int_as_float(
            __builtin_amdgcn_readlane(__float_as_int(yh), 2 * p));
        const float gy = __int_as_float(
            __builtin_amdgcn_readlane(__float_as_int(yh), 2 * p - 1));
        A[8 + p] = (f32x2){ is63 ? gx : dx, is63 ? gy : dy };
    }

    // ---- right edge: ypad[m>16383] = y[16383]  (h[6..10]=h[5]) ----
    if (RIGHT) {
        if (N == T_LEN - OPT) {
            const float h5 = A[11].y;
            A[11] = (f32x2){ h5, h5 };
            A[12] = (f32x2){ h5, h5 };
            A[13] = (f32x2){ h5, h5 };
        }
    }

    // ---- downsample, packed: o_r = sum_j dpair[j] (.) A[r+j+1] ----
    float o[OPT];
#pragma unroll
    for (int r = 0; r < OPT; ++r) {
        f32x2 P = dpair[0] * A[r + 1];
#pragma unroll
        for (int j = 1; j < 6; ++j)
            P = __builtin_elementwise_fma(dpair[j], A[r + j + 1], P);
        o[r] = P.x + P.y;
    }

    *reinterpret_cast<float4*>(orow + N)     = make_float4(o[0], o[1], o[2], o[3]);
    *reinterpret_cast<float4*>(orow + N + 4) = make_float4(o[4], o[5], o[6], o[7]);
}

__global__ __launch_bounds__(BLOCK, 4) void act1d_fused(
    const float* __restrict__ x,
    const float* __restrict__ alpha,
    const float* __restrict__ wup_g,
    const float* __restrict__ wdn_g,
    float* __restrict__ out)
{
    const int bx   = blockIdx.x;
    const int p    = bx & 1;            // segment-pair selector
    const int bc   = bx >> 1;           // row index b*C + c
    const int c    = bc & (C_N - 1);
    const int tid  = threadIdx.x;
    const int lane = tid & 63;
    const int s_   = lane >> 1;
    const int par  = lane & 1;
    const int b63  = OPT * (tid - lane + 63);   // lane-63 N offset (wave-uniform)

    const float* __restrict__ xrow = x   + (size_t)bc * T_LEN;
    float*       __restrict__ orow = out + (size_t)bc * T_LEN;

    const int NA = p * TCHUNK + OPT * tid;      // chunk p   (0 or 1)
    const int NB = NA + 2 * TCHUNK;             // chunk p+2 (2 or 3)

    // ================= ALL VMEM ISSUED UP FRONT =================
    float xrA[16], xtA[6], xrB[16], xtB[6];

    // A window: xrA[u] = xc[NA-8+u] (left clamp only when NA==0)
    if (NA >= 8) {
#pragma unroll
        for (int w = 0; w < 4; ++w) {
            const float4 t4 = *reinterpret_cast<const float4*>(xrow + NA - 8 + 4 * w);
            xrA[4 * w + 0] = t4.x;
            xrA[4 * w + 1] = t4.y;
            xrA[4 * w + 2] = t4.z;
            xrA[4 * w + 3] = t4.w;
        }
    } else {
#pragma unroll
        for (int u = 0; u < 16; ++u)
            xrA[u] = xrow[max(NA - 8 + u, 0)];
    }
    // A halo taps: N63A + 12 < T_LEN always (p<=1)
    {
        const int hbA = p * TCHUNK + b63 + 2 + s_ + par;
#pragma unroll
        for (int j = 0; j < 6; ++j)
            xtA[j] = xrow[hbA + j];
    }
    // B window: never clamps (4088 <= NB-8, NB+7 <= 8191)
    {
        const float* pb = xrow + NB - 8;
#pragma unroll
        for (int w = 0; w < 4; ++w) {
            const float4 t4 = *reinterpret_cast<const float4*>(pb + 4 * w);
            xrB[4 * w + 0] = t4.x;
            xrB[4 * w + 1] = t4.y;
            xrB[4 * w + 2] = t4.z;
            xrB[4 * w + 3] = t4.w;
        }
    }
    // B halo taps: clamp only for last wave of chunk 3
    {
        const int N63B = (p + 2) * TCHUNK + b63;
        const int hbB  = N63B + 2 + s_ + par;
        if (N63B + 12 < T_LEN) {         // wave-uniform fast path
#pragma unroll
            for (int j = 0; j < 6; ++j)
                xtB[j] = xrow[hbB + j];
        } else {
#pragma unroll
            for (int j = 0; j < 6; ++j)
                xtB[j] = xrow[min(hbB + j, T_LEN - 1)];
        }
    }

    // ---- pin: loads stay above, compute below (waits land at use) ----
    asm volatile("" ::: "memory");
    __builtin_amdgcn_sched_barrier(0);

    // ---- uniform constants (wave-uniform -> SGPRs) ----
    f32x2 cpair[6], dpair[6];
#pragma unroll
    for (int t = 0; t < 6; ++t) {
        cpair[t] = (f32x2){ wup_g[2 * t + 1] + wup_g[2 * t + 1],
                            wup_g[2 * t]     + wup_g[2 * t] };
        dpair[t] = (f32x2){ wdn_g[2 * t + 1], wdn_g[2 * t] };
    }
    const float a     = __expf(alpha[c]);
    const float inv_a = 1.0f / (a + 1e-9f);
    const float ka    = a * INV_2PI;    // v_sin_f32 takes revolutions
    const f32x2 ka2   = (f32x2){ ka, ka };
    const f32x2 inva2 = (f32x2){ inv_a, inv_a };

    // ---- segment A (left edge possible), then B (right edge possible);
    //      B's loads completed during A's compute ----
    compute_store<true,  false>(xrA, xtA, NA, lane, par, orow,
                                cpair, dpair, inv_a, ka, ka2, inva2);
    compute_store<false, true >(xrB, xtB, NB, lane, par, orow,
                                cpair, dpair, inv_a, ka, ka2, inva2);
}

extern "C" void kernel_launch(void* const* d_in, const int* in_sizes, int n_in,
                              void* d_out, int out_size, void* d_ws, size_t ws_size,
                              hipStream_t stream)
{
    const float* x     = (const float*)d_in[0];
    const float* alpha = (const float*)d_in[1];
    const float* wup   = (const float*)d_in[2];
    const float* wdn   = (const float*)d_in[3];
    float*       out   = (float*)d_out;

    const int B_N  = out_size / (C_N * T_LEN);   // 8
    const int grid = B_N * C_N * 2;              // 8192 (row x segment-pair)

    act1d_fused<<<grid, BLOCK, 0, stream>>>(x, alpha, wup, wdn, out);
}